// Round 3
// baseline (412.175 us; speedup 1.0000x reference)
//
#include <hip/hip_runtime.h>
#include <math.h>

// Problem constants (B=4, L=8192, SEG=2048, RATE=4, D=768)
#define SEGLEN 2048
#define SRATE 4
#define DIM 768
#define BATCH 4
#define LFULL 8192
#define LSP 2048                 // sparsified length per batch (4 segs * 512)
#define NROWS (BATCH * LSP)      // 8192 total sparsified rows
#define LN_EPS 1e-5f
#define ATT_SCALE 0.03608439182435161f   // 1/sqrt(768)

typedef __attribute__((ext_vector_type(8))) short s16x8;
typedef __attribute__((ext_vector_type(4))) float f32x4;

__device__ __forceinline__ ushort f2bf(float f) {
    unsigned u = __float_as_uint(f);
    u += 0x7fffu + ((u >> 16) & 1u);      // RNE
    return (ushort)(u >> 16);
}
__device__ __forceinline__ float bf2f(ushort h) {
    return __uint_as_float(((unsigned)h) << 16);
}

// async global->LDS, 16B per lane. LDS dest is wave-uniform base + lane*16.
__device__ __forceinline__ void ld_lds16(const ushort* g, ushort* l) {
    __builtin_amdgcn_global_load_lds(
        (const __attribute__((address_space(1))) void*)g,
        (__attribute__((address_space(3))) void*)l, 16, 0, 0);
}

// ---------------------------------------------------------------------------
// Gather sparsified rows (every RATE-th within each segment) + fp32->bf16.
// ---------------------------------------------------------------------------
__global__ void pack3(const float* __restrict__ Q, const float* __restrict__ Ks,
                      const float* __restrict__ V, ushort* __restrict__ X) {
    const float* src = blockIdx.z == 0 ? Q : blockIdx.z == 1 ? Ks : V;
    ushort* dst = X + (long)blockIdx.z * (NROWS * DIM);
    int idx = blockIdx.x * 256 + threadIdx.x;        // one per 4 elements
    int r  = idx / (DIM / 4);
    int dg = idx - r * (DIM / 4);
    int bb = r >> 11;            // /2048
    int s  = r & 2047;
    int seg = s >> 9;            // /512
    int j   = s & 511;
    long srow = (long)bb * LFULL + seg * SEGLEN + j * SRATE;
    float4 f = *(const float4*)(src + srow * DIM + dg * 4);
    ushort4 o;
    o.x = f2bf(f.x); o.y = f2bf(f.y); o.z = f2bf(f.z); o.w = f2bf(f.w);
    *(ushort4*)(dst + (long)r * DIM + dg * 4) = o;
}

// weights fp32 -> bf16, z selects Wq/Wk/Wv; dst contiguous
__global__ void conv3(const float* __restrict__ Wq, const float* __restrict__ Wk,
                      const float* __restrict__ Wv, ushort* __restrict__ W) {
    const float* src = blockIdx.z == 0 ? Wq : blockIdx.z == 1 ? Wk : Wv;
    ushort* dst = W + (long)blockIdx.z * (DIM * DIM);
    int idx = blockIdx.x * 256 + threadIdx.x;
    float4 f = *(const float4*)(src + (long)idx * 4);
    ushort4 o;
    o.x = f2bf(f.x); o.y = f2bf(f.y); o.z = f2bf(f.z); o.w = f2bf(f.w);
    *(ushort4*)(dst + (long)idx * 4) = o;
}

// ---------------------------------------------------------------------------
// Projection BT-GEMM (unchanged from round 2, proj mode only).
// 128x128 tile, BK=64, 256 thr = 4 waves (2x2), wave tile 64x64.
// ---------------------------------------------------------------------------
__global__ __launch_bounds__(256, 2) void gemm_proj(
    const ushort* __restrict__ Ag, const ushort* __restrict__ Bg,
    ushort* __restrict__ Cb, ushort* __restrict__ Cb2,
    int lda, int ldb, long sA, long sB, long sC, int ldc)
{
    __shared__ ushort lds[2][2][8192];   // 64 KiB

    const int gx = gridDim.x, gy = gridDim.y;
    const int G = gx * gy * gridDim.z;
    const int f = blockIdx.x + gx * (blockIdx.y + gy * blockIdx.z);
    const int wg = (f & 7) * (G >> 3) + (f >> 3);
    const int bx = wg % gx;
    const int rest = wg / gx;
    const int by = rest % gy;
    const int z  = rest / gy;

    const ushort* Aop = Ag;                    // A shared across z (Xq,Xk,Xv contig via sA)
    const ushort* Bop = Bg + (long)z * sB;
    const ushort* Az  = Aop + (long)z * sA;

    const int tid = threadIdx.x;
    const int wid = tid >> 6, lane = tid & 63;
    const int wm = wid >> 1, wn = wid & 1;
    const int quad = lane >> 4, lr = lane & 15;
    const int rowBase = by * 128;
    const int colBase = bx * 128;

    int ib = ((lane & 15) << 6) | ((lane >> 4) << 4);
    ib ^= ((ib >> 9) & 1) << 5;

    long offA[4], offB[4];
#pragma unroll
    for (int i = 0; i < 4; i++) {
        int c = i * 256 + tid;
        int cc = c ^ (((c >> 5) & 1) << 1);
        int s = cc >> 6;
        int row  = ((s >> 1) << 4) + ((cc >> 2) & 15);
        int colE = ((s & 1) << 5) + ((cc & 3) << 3);
        offA[i] = (long)(rowBase + row) * lda + colE;
        offB[i] = (long)(colBase + row) * ldb + colE;
    }

    const int NT = DIM >> 6;   // 12

#define STA(buf, vv, i) ld_lds16(Az + offA[i] + (long)(vv) * 64, &lds[buf][0][(i) * 2048 + wid * 512])
#define STB(buf, vv, i) ld_lds16(Bop + offB[i] + (long)(vv) * 64, &lds[buf][1][(i) * 2048 + wid * 512])

#pragma unroll
    for (int i = 0; i < 4; i++) { STA(0, 0, i); STB(0, 0, i); }
    asm volatile("s_waitcnt vmcnt(0)" ::: "memory");
    __builtin_amdgcn_s_barrier();

    f32x4 acc[4][4] = {};

    for (int v = 0; v < NT; ++v) {
        const int b = v & 1;
        if (v + 1 < NT) {
#pragma unroll
            for (int i = 0; i < 4; i++) { STA(b ^ 1, v + 1, i); STB(b ^ 1, v + 1, i); }
        }
        const char* lA = (const char*)&lds[b][0][0];
        const char* lB = (const char*)&lds[b][1][0];
#pragma unroll
        for (int ks = 0; ks < 2; ++ks) {
            s16x8 af[4], bfm[4];
#pragma unroll
            for (int t = 0; t < 4; ++t)
                af[t] = *(const s16x8*)(lA + (((wm * 4 + t) * 2 + ks) << 10) + ib);
#pragma unroll
            for (int t = 0; t < 4; ++t)
                bfm[t] = *(const s16x8*)(lB + (((wn * 4 + t) * 2 + ks) << 10) + ib);
            __builtin_amdgcn_s_setprio(1);
#pragma unroll
            for (int i = 0; i < 4; i++)
#pragma unroll
                for (int j = 0; j < 4; j++)
                    acc[i][j] = __builtin_amdgcn_mfma_f32_16x16x32_bf16(
                        af[i], bfm[j], acc[i][j], 0, 0, 0);
            __builtin_amdgcn_s_setprio(0);
        }
        if (v + 1 < NT) asm volatile("s_waitcnt vmcnt(0)" ::: "memory");
        __builtin_amdgcn_s_barrier();
    }
#undef STA
#undef STB

    if (z < 2) {
        ushort* Cz = Cb + (long)z * sC;
#pragma unroll
        for (int i = 0; i < 4; i++) {
            int r0 = rowBase + wm * 64 + i * 16 + quad * 4;
#pragma unroll
            for (int j = 0; j < 4; j++) {
                int c = colBase + wn * 64 + j * 16 + lr;
#pragma unroll
                for (int reg = 0; reg < 4; reg++)
                    Cz[(long)(r0 + reg) * ldc + c] = f2bf(acc[i][j][reg]);
            }
        }
    } else {
        // v-projection: store transposed vT[b][col][row]
#pragma unroll
        for (int i = 0; i < 4; i++) {
            int r0 = rowBase + wm * 64 + i * 16 + quad * 4;
            int bidx = r0 >> 11;
            int jj = r0 & 2047;
            ushort* Cz = Cb2 + (long)bidx * DIM * LSP;
#pragma unroll
            for (int j = 0; j < 4; j++) {
                int c = colBase + wn * 64 + j * 16 + lr;
                ushort4 o;
                o.x = f2bf(acc[i][j][0]); o.y = f2bf(acc[i][j][1]);
                o.z = f2bf(acc[i][j][2]); o.w = f2bf(acc[i][j][3]);
                *(ushort4*)(Cz + (long)c * LSP + jj) = o;
            }
        }
    }
}

// ---------------------------------------------------------------------------
// Fused attention: per block, QBLK=64 q-rows x kv-quarter (512 kv rows).
// O_partial[kvq] = sum_kv exp(scale*q.k) * v ; l += rowsum(exp) (atomic).
// No max-subtraction needed (bounded logits; proven rounds 1-2).
// 512 thr = 8 waves. QK: wave grid 2x4 (wave S-tile 32x32), 12 k-chunks of 64,
// triple-buffered with counted vmcnt(3). P via 16KB XOR-swizzled LDS.
// PV: 6 d-chunks of 128 (vT staged, st_16x32), acc_o[6][2][2] = 96 VGPR.
// LDS: P 16KB + staging 72KB = 88KB.
// ---------------------------------------------------------------------------
__global__ __launch_bounds__(512) void attn_fused(
    const ushort* __restrict__ qb, const ushort* __restrict__ kb,
    const ushort* __restrict__ vT, float* __restrict__ Op,
    float* __restrict__ l)
{
    __shared__ ushort P_lds[8192];    // 16 KB: P [64][128] bf16, swizzled
    __shared__ ushort sh[36864];      // 72 KB: QK 3x(Q 4096 + K 8192); V aliases

    // XCD grouping: xcd hosts 2 (batch,kvq) groups -> K/V quarters L2-resident
    const int p = blockIdx.x + 4 * blockIdx.y;       // 0..511
    const int xcd = p & 7, idx = p >> 3;             // idx 0..63
    const int g = xcd + 8 * (idx >> 5);              // group 0..15
    const int m = idx & 31;
    const int bb = g >> 2, kvq = g & 3;
    const int qt = bb * 32 + m;                      // global q-tile (64 rows)
    const int kv0 = kvq * 512;

    const int tid = threadIdx.x;
    const int w = tid >> 6, lane = tid & 63;
    const int wm = w >> 2, wn = w & 3;               // 2 x 4 wave grid
    const int quad = lane >> 4, lr = lane & 15;

    int ib = ((lane & 15) << 6) | ((lane >> 4) << 4);
    ib ^= ((ib >> 9) & 1) << 5;

    // staging source offsets (inverse-swizzled st_16x32), per-thread
    // Q tile 64x64: chunk c = tid
    long offQ; long offK[2]; long offV[4];
    {
        int c = tid;
        int cc = c ^ (((c >> 5) & 1) << 1);
        int s = cc >> 6;
        int row  = ((s >> 1) << 4) + ((cc >> 2) & 15);
        int colE = ((s & 1) << 5) + ((cc & 3) << 3);
        offQ = ((long)(qt * 64 + row)) * DIM + colE;
#pragma unroll
        for (int i = 0; i < 2; i++) {
            int c2 = i * 512 + tid;
            int cc2 = c2 ^ (((c2 >> 5) & 1) << 1);
            int s2 = cc2 >> 6;
            int r2 = ((s2 >> 1) << 4) + ((cc2 >> 2) & 15);
            int e2 = ((s2 & 1) << 5) + ((cc2 & 3) << 3);
            offK[i] = (long)r2 * DIM + e2;
        }
#pragma unroll
        for (int i = 0; i < 4; i++) {
            int c4 = i * 512 + tid;
            int cc4 = c4 ^ (((c4 >> 5) & 1) << 1);
            int s4 = cc4 >> 6;                        // 0..31 (8 rowgrp x 4 colgrp)
            int r4 = ((s4 >> 2) << 4) + ((cc4 >> 2) & 15);
            int e4 = ((s4 & 3) << 5) + ((cc4 & 3) << 3);
            offV[i] = (long)r4 * LSP + e4;
        }
    }

    f32x4 acc_o[6][2][2] = {};
    float lp[2][4] = {};

    for (int tt = 0; tt < 4; ++tt) {
        const int kvin = kv0 + tt * 128;
        const long kbase = ((long)bb * LSP + kvin) * DIM;           // K row base
        const long vbase = (long)bb * DIM * LSP + kvin;             // vT base (d=0)

        // prologue: stage QK chunks 0,1 (bufs 0,1); wait chunk 0
        ld_lds16(qb + offQ, sh + w * 512);
        ld_lds16(kb + kbase + offK[0], sh + 4096 + w * 512);
        ld_lds16(kb + kbase + offK[1], sh + 8192 + w * 512);
        ld_lds16(qb + offQ + 64, sh + 12288 + w * 512);
        ld_lds16(kb + kbase + offK[0] + 64, sh + 12288 + 4096 + w * 512);
        ld_lds16(kb + kbase + offK[1] + 64, sh + 12288 + 8192 + w * 512);
        asm volatile("s_waitcnt vmcnt(3)" ::: "memory");
        __builtin_amdgcn_s_barrier();

        f32x4 acc_s[2][2] = {};
        int buf = 0;
        for (int kc = 0; kc < 12; ++kc) {
            if (kc < 10) {               // stage chunk kc+2 (3-deep)
                const int nb = (buf == 2) ? 0 : ((buf == 1) ? 2 : 1);
                const int nb2 = (nb == 2) ? 0 : nb + 1;   // (kc+2)%3 buffer
                (void)nb;
                ld_lds16(qb + offQ + (kc + 2) * 64, sh + nb2 * 12288 + w * 512);
                ld_lds16(kb + kbase + offK[0] + (kc + 2) * 64, sh + nb2 * 12288 + 4096 + w * 512);
                ld_lds16(kb + kbase + offK[1] + (kc + 2) * 64, sh + nb2 * 12288 + 8192 + w * 512);
            } else if (kc == 10) {       // V chunk 0, first half -> [0..8192)
                ld_lds16(vT + vbase + offV[0], sh + w * 512);
                ld_lds16(vT + vbase + offV[1], sh + 4096 + w * 512);
            } else {                     // kc==11: V chunk 0, second half
                ld_lds16(vT + vbase + offV[2], sh + 8192 + w * 512);
                ld_lds16(vT + vbase + offV[3], sh + 12288 + w * 512);
            }
            const char* lA = (const char*)(sh + buf * 12288);
            const char* lB = (const char*)(sh + buf * 12288 + 4096);
            s16x8 aq[2][2], bq[2][2];
#pragma unroll
            for (int i = 0; i < 2; i++)
#pragma unroll
                for (int ks = 0; ks < 2; ks++)
                    aq[i][ks] = *(const s16x8*)(lA + (((wm * 2 + i) * 2 + ks) << 10) + ib);
#pragma unroll
            for (int j = 0; j < 2; j++)
#pragma unroll
                for (int ks = 0; ks < 2; ks++)
                    bq[j][ks] = *(const s16x8*)(lB + (((wn * 2 + j) * 2 + ks) << 10) + ib);
            __builtin_amdgcn_s_setprio(1);
#pragma unroll
            for (int i = 0; i < 2; i++)
#pragma unroll
                for (int j = 0; j < 2; j++)
#pragma unroll
                    for (int ks = 0; ks < 2; ks++)
                        acc_s[i][j] = __builtin_amdgcn_mfma_f32_16x16x32_bf16(
                            aq[i][ks], bq[j][ks], acc_s[i][j], 0, 0, 0);
            __builtin_amdgcn_s_setprio(0);
            if (kc < 10)      asm volatile("s_waitcnt vmcnt(3)" ::: "memory");
            else if (kc == 10) asm volatile("s_waitcnt vmcnt(2)" ::: "memory");
            __builtin_amdgcn_s_barrier();
            buf = (buf == 2) ? 0 : buf + 1;
        }

        // exp + l-partials + P -> LDS (swizzled)
        char* Pl = (char*)P_lds;
#pragma unroll
        for (int i = 0; i < 2; i++)
#pragma unroll
            for (int j = 0; j < 2; j++)
#pragma unroll
                for (int reg = 0; reg < 4; reg++)
                    acc_s[i][j][reg] = __expf(acc_s[i][j][reg] * ATT_SCALE);
#pragma unroll
        for (int i = 0; i < 2; i++)
#pragma unroll
            for (int reg = 0; reg < 4; reg++) {
                float s = acc_s[i][0][reg] + acc_s[i][1][reg];
                s += __shfl_xor(s, 1, 64);
                s += __shfl_xor(s, 2, 64);
                s += __shfl_xor(s, 4, 64);
                s += __shfl_xor(s, 8, 64);
                lp[i][reg] += s;
            }
#pragma unroll
        for (int i = 0; i < 2; i++)
#pragma unroll
            for (int j = 0; j < 2; j++)
#pragma unroll
            for (int reg = 0; reg < 4; reg++) {
                int r = wm * 32 + i * 16 + quad * 4 + reg;
                int pb = (r << 8) + ((wn * 32 + j * 16 + lr) << 1);
                pb ^= (r & 7) << 4;
                *(ushort*)(Pl + pb) = f2bf(acc_s[i][j][reg]);
            }
        __syncthreads();   // P visible; V chunk 0 drained (syncthreads waits vm)

        // PV: read P frags once, loop 6 d-chunks (V dbuf in sh[0..32768))
        s16x8 pa[2][4];
#pragma unroll
        for (int i = 0; i < 2; i++)
#pragma unroll
            for (int ks = 0; ks < 4; ks++) {
                int r = wm * 32 + i * 16 + (lane & 15);
                int pb = (r << 8) + ks * 64 + quad * 16;
                pb ^= (r & 7) << 4;
                pa[i][ks] = *(const s16x8*)(Pl + pb);
            }
#pragma unroll
        for (int dc = 0; dc < 6; ++dc) {
            const int vb = dc & 1;
            if (dc < 5) {
                const long vb2 = vbase + (long)((dc + 1) * 128) * LSP;
#pragma unroll
                for (int i = 0; i < 4; i++)
                    ld_lds16(vT + vb2 + offV[i], sh + (vb ^ 1) * 16384 + i * 4096 + w * 512);
            }
            const char* lV = (const char*)(sh + vb * 16384);
            s16x8 vq[2][4];
#pragma unroll
            for (int j = 0; j < 2; j++)
#pragma unroll
                for (int ks = 0; ks < 4; ks++)
                    vq[j][ks] = *(const s16x8*)(lV + (((wn * 2 + j) * 4 + ks) << 10) + ib);
            __builtin_amdgcn_s_setprio(1);
#pragma unroll
            for (int i = 0; i < 2; i++)
#pragma unroll
                for (int j = 0; j < 2; j++)
#pragma unroll
                    for (int ks = 0; ks < 4; ks++)
                        acc_o[dc][i][j] = __builtin_amdgcn_mfma_f32_16x16x32_bf16(
                            pa[i][ks], vq[j][ks], acc_o[dc][i][j], 0, 0, 0);
            __builtin_amdgcn_s_setprio(0);
            if (dc < 5) asm volatile("s_waitcnt vmcnt(0)" ::: "memory");
            __builtin_amdgcn_s_barrier();
        }
    }

    // epilogue: l atomics + O partial
    if (lr == 0) {
#pragma unroll
        for (int i = 0; i < 2; i++)
#pragma unroll
            for (int reg = 0; reg < 4; reg++)
                atomicAdd(&l[qt * 64 + wm * 32 + i * 16 + quad * 4 + reg], lp[i][reg]);
    }
    float* Out = Op + (long)kvq * NROWS * DIM;
#pragma unroll
    for (int dc = 0; dc < 6; ++dc)
#pragma unroll
        for (int i = 0; i < 2; i++)
#pragma unroll
            for (int j = 0; j < 2; j++)
#pragma unroll
                for (int reg = 0; reg < 4; reg++) {
                    int row = qt * 64 + wm * 32 + i * 16 + quad * 4 + reg;
                    int col = dc * 128 + wn * 32 + j * 16 + lr;
                    Out[(long)row * DIM + col] = acc_o[dc][i][j][reg];
                }
}

// ---------------------------------------------------------------------------
// In-place LayerNorm over DIM=768 bf16 values. One wave per row (12 elem/lane).
// ---------------------------------------------------------------------------
__global__ __launch_bounds__(256) void ln_inplace(
    ushort* __restrict__ X, const float* __restrict__ gamma,
    const float* __restrict__ beta)
{
    int wid = threadIdx.x >> 6, lane = threadIdx.x & 63;
    int row = blockIdx.x * 4 + wid;
    ushort* xp = X + (long)row * DIM;
    float v[12];
    float s = 0.f;
#pragma unroll
    for (int c = 0; c < 12; c++) { v[c] = bf2f(xp[c * 64 + lane]); s += v[c]; }
    for (int m = 1; m < 64; m <<= 1) s += __shfl_xor(s, m, 64);
    float mean = s * (1.0f / 768.0f);
    float q = 0.f;
#pragma unroll
    for (int c = 0; c < 12; c++) { float d = v[c] - mean; q += d * d; }
    for (int m = 1; m < 64; m <<= 1) q += __shfl_xor(q, m, 64);
    float rstd = rsqrtf(q * (1.0f / 768.0f) + LN_EPS);
#pragma unroll
    for (int c = 0; c < 12; c++) {
        int idx = c * 64 + lane;
        float y = (v[c] - mean) * rstd * gamma[idx] + beta[idx];
        xp[idx] = f2bf(y);
    }
}

// ---------------------------------------------------------------------------
// out[row] = softmax_over_d( (sum of 4 O-partials)[row] / l[row] ).
// ---------------------------------------------------------------------------
__global__ __launch_bounds__(256) void final_softmax4(
    const float* __restrict__ Op, const float* __restrict__ l,
    float* __restrict__ out)
{
    int wid = threadIdx.x >> 6, lane = threadIdx.x & 63;
    int row = blockIdx.x * 4 + wid;
    long base = (long)row * DIM;
    const long ps = (long)NROWS * DIM;
    float inv = 1.0f / l[row];
    float v[12]; float mx = -1e30f;
#pragma unroll
    for (int c = 0; c < 12; c++) {
        long o = base + c * 64 + lane;
        v[c] = (Op[o] + Op[o + ps] + Op[o + 2 * ps] + Op[o + 3 * ps]) * inv;
        mx = fmaxf(mx, v[c]);
    }
    for (int m = 1; m < 64; m <<= 1) mx = fmaxf(mx, __shfl_xor(mx, m, 64));
    float s = 0.f;
#pragma unroll
    for (int c = 0; c < 12; c++) { v[c] = __expf(v[c] - mx); s += v[c]; }
    for (int m = 1; m < 64; m <<= 1) s += __shfl_xor(s, m, 64);
    float invs = 1.0f / s;
#pragma unroll
    for (int c = 0; c < 12; c++) out[base + c * 64 + lane] = v[c] * invs;
}

// ---------------------------------------------------------------------------
extern "C" void kernel_launch(void* const* d_in, const int* in_sizes, int n_in,
                              void* d_out, int out_size, void* d_ws, size_t ws_size,
                              hipStream_t stream)
{
    const float* Q  = (const float*)d_in[0];
    const float* K_ = (const float*)d_in[1];
    const float* V  = (const float*)d_in[2];
    const float* Wq = (const float*)d_in[3];
    const float* Wk = (const float*)d_in[4];
    const float* Wv = (const float*)d_in[5];
    const float* g  = (const float*)d_in[6];
    const float* b  = (const float*)d_in[7];
    float* out = (float*)d_out;

    char* ws = (char*)d_ws;
    // Workspace layout (bytes), ~179.7 MB total, no aliasing.
    ushort* Xq  = (ushort*)(ws + 0);            // 37,748,736 (Xq,Xk,Xv contig)
    ushort* Wqb = (ushort*)(ws + 37748736);     // 3,538,944
    ushort* qb  = (ushort*)(ws + 41287680);     // 12,582,912
    ushort* kb  = (ushort*)(ws + 53870592);     // 12,582,912
    ushort* vT  = (ushort*)(ws + 66453504);     // 12,582,912
    float*  Op  = (float*)(ws + 79036416);      // 4 x 25,165,824 partials
    float*  l   = (float*)(ws + 179699712);     // 32,768

    (void)in_sizes; (void)n_in; (void)out_size; (void)ws_size;

    hipMemsetAsync(l, 0, NROWS * sizeof(float), stream);

    // 1) gather sparsified rows -> bf16 (z = Q/K/V)
    pack3<<<dim3(6144, 1, 3), 256, 0, stream>>>(Q, K_, V, Xq);
    // 2) weights -> bf16 (z = Wq/Wk/Wv)
    conv3<<<dim3(576, 1, 3), 256, 0, stream>>>(Wq, Wk, Wv, Wqb);

    // 3) projections: z in {q,k,v}; v stores transposed (vT). 1152 blocks.
    gemm_proj<<<dim3(DIM / 128, NROWS / 128, 3), 256, 0, stream>>>(
        Xq, Wqb, qb, vT,
        DIM, DIM, (long)NROWS * DIM, (long)DIM * DIM, (long)NROWS * DIM, DIM);

    // 4) LayerNorm q and k in place (qb,kb contiguous: 16384 rows)
    ln_inplace<<<4096, 256, 0, stream>>>(qb, g, b);

    // 5) fused attention: 512 blocks (4 kv-quarters x 128 q-tiles)
    attn_fused<<<dim3(4, 128), 512, 0, stream>>>(qb, kb, vT, Op, l);

    // 6) out = softmax_d(sum(Op partials) / l)
    final_softmax4<<<2048, 256, 0, stream>>>(Op, l, out);
}

// Round 5
// 383.771 us; speedup vs baseline: 1.0740x; 1.0740x over previous
//
#include <hip/hip_runtime.h>
#include <math.h>

// Problem constants (B=4, L=8192, SEG=2048, RATE=4, D=768)
#define SEGLEN 2048
#define SRATE 4
#define DIM 768
#define BATCH 4
#define LFULL 8192
#define LSP 2048                 // sparsified length per batch (4 segs * 512)
#define NROWS (BATCH * LSP)      // 8192 total sparsified rows
#define LN_EPS 1e-5f
#define ATT_SCALE 0.03608439182435161f   // 1/sqrt(768)

typedef __attribute__((ext_vector_type(8))) short s16x8;
typedef __attribute__((ext_vector_type(4))) float f32x4;

__device__ __forceinline__ ushort f2bf(float f) {
    unsigned u = __float_as_uint(f);
    u += 0x7fffu + ((u >> 16) & 1u);      // RNE
    return (ushort)(u >> 16);
}
__device__ __forceinline__ float bf2f(ushort h) {
    return __uint_as_float(((unsigned)h) << 16);
}

// async global->LDS, 16B per lane. LDS dest is wave-uniform base + lane*16.
__device__ __forceinline__ void ld_lds16(const ushort* g, ushort* l) {
    __builtin_amdgcn_global_load_lds(
        (const __attribute__((address_space(1))) void*)g,
        (__attribute__((address_space(3))) void*)l, 16, 0, 0);
}

// ---------------------------------------------------------------------------
// Gather sparsified rows (every RATE-th within each segment) + fp32->bf16.
// ---------------------------------------------------------------------------
__global__ void pack3(const float* __restrict__ Q, const float* __restrict__ Ks,
                      const float* __restrict__ V, ushort* __restrict__ X) {
    const float* src = blockIdx.z == 0 ? Q : blockIdx.z == 1 ? Ks : V;
    ushort* dst = X + (long)blockIdx.z * (NROWS * DIM);
    int idx = blockIdx.x * 256 + threadIdx.x;        // one per 4 elements
    int r  = idx / (DIM / 4);
    int dg = idx - r * (DIM / 4);
    int bb = r >> 11;            // /2048
    int s  = r & 2047;
    int seg = s >> 9;            // /512
    int j   = s & 511;
    long srow = (long)bb * LFULL + seg * SEGLEN + j * SRATE;
    float4 f = *(const float4*)(src + srow * DIM + dg * 4);
    ushort4 o;
    o.x = f2bf(f.x); o.y = f2bf(f.y); o.z = f2bf(f.z); o.w = f2bf(f.w);
    *(ushort4*)(dst + (long)r * DIM + dg * 4) = o;
}

// weights fp32 -> bf16, z selects Wq/Wk/Wv; dst contiguous
__global__ void conv3(const float* __restrict__ Wq, const float* __restrict__ Wk,
                      const float* __restrict__ Wv, ushort* __restrict__ W) {
    const float* src = blockIdx.z == 0 ? Wq : blockIdx.z == 1 ? Wk : Wv;
    ushort* dst = W + (long)blockIdx.z * (DIM * DIM);
    int idx = blockIdx.x * 256 + threadIdx.x;
    float4 f = *(const float4*)(src + (long)idx * 4);
    ushort4 o;
    o.x = f2bf(f.x); o.y = f2bf(f.y); o.z = f2bf(f.z); o.w = f2bf(f.w);
    *(ushort4*)(dst + (long)idx * 4) = o;
}

// ---------------------------------------------------------------------------
// BT-GEMM: C[i][j] = sum_k A[i][k]*B[j][k], bf16 operands K-contiguous.
// 128x128 tile, BK=64, 256 thr = 4 waves (2x2), wave tile 64x64 (acc[4][4]).
// 64 KiB LDS -> 2 blocks/CU co-resident.
// DEEP PIPELINE: LDS subtiles are ks-PURE — chunks {0,1} hold K-half 0
// (els 0..31), chunks {2,3} hold K-half 1. Each half of a buffer is dead
// after its own compute phase, so staging runs 3 phases ahead:
//   phase ks0(v): wait vmcnt(8); barrier; issue H1(v+1); read+MFMA ks0
//   phase ks1(v): wait vmcnt(8); barrier; issue H0(v+2); read+MFMA ks1
// In-flight span = 1.5 tiles (~700cy >= HBM latency); never vmcnt(0) in
// steady state (T4). Race-safe: every gload's target region's last readers
// completed before the barrier preceding the issue (ds_read results consumed
// by MFMA behind compiler lgkmcnt before the wave reaches the barrier);
// per-wave vmcnt->barrier gives the collective staging guarantee.
//   - subtiled st_16x32 swizzle (0 bank conflicts measured), gload_lds linear
//     dest + inverse-swizzled global source (rule #21).
//   - m204 bijective XCD chunking (all grids %8==0).
// MODE 0: z<2 -> bf16 row-major to Cb+z*sC; z==2 -> transposed vT to Cb2 [proj]
// MODE 2: e=__expf(acc*scale); bf16 P row-major + atomicAdd row-sums     [QK]
// MODE 3: split-K: z=(batch,half); fp32 row-major to (half? Cf2 : Cf)   [PV]
// ---------------------------------------------------------------------------
template<int MODE, int NT>
__global__ __launch_bounds__(256, 2) void gemm_bt(
    const ushort* __restrict__ Ag, const ushort* __restrict__ Bg,
    ushort* __restrict__ Cb, ushort* __restrict__ Cb2,
    float* __restrict__ Cf, float* __restrict__ Cf2, float* __restrict__ lsum,
    int M, int N, int lda, int ldb, long sA, long sB, long sC,
    int ldc, float scale)
{
    __shared__ ushort lds[2][2][8192];   // [dbuf][A/B][16KB] = 64 KiB
    const int K = NT * 64;

    // --- XCD-chunked bijective remap (m204; grid sizes all divisible by 8)
    const int gx = gridDim.x, gy = gridDim.y;
    const int G = gx * gy * gridDim.z;
    const int f = blockIdx.x + gx * (blockIdx.y + gy * blockIdx.z);
    const int wg = (f & 7) * (G >> 3) + (f >> 3);
    const int bx = wg % gx;
    const int rest = wg / gx;
    const int by = rest % gy;
    const int z  = rest / gy;

    const int bz = (MODE == 3) ? (z >> 1) : z;
    const int hz = (MODE == 3) ? (z & 1) : 0;
    const ushort* Aop = Ag + (long)bz * sA + (long)hz * K;
    const ushort* Bop = Bg + (long)bz * sB + (long)hz * K;

    const int tid = threadIdx.x;
    const int wid = tid >> 6, lane = tid & 63;
    const int wm = wid >> 1, wn = wid & 1;      // 2x2 wave grid
    const int quad = lane >> 4, lr = lane & 15;
    const int rowBase = by * 128;
    const int colBase = bx * 128;

    // per-lane ds_read byte offset within a 1024B (16x32) subtile, swizzled
    int ib = ((lane & 15) << 6) | ((lane >> 4) << 4);
    ib ^= ((ib >> 9) & 1) << 5;

    // staging: chunk c = i*256+tid -> linear 16B LDS dest; global source is
    // the inverse-swizzled chunk. Subtile order is ks-pure: s'=ks*8+rowgrp.
    long offA[4], offB[4];
#pragma unroll
    for (int i = 0; i < 4; i++) {
        int c = i * 256 + tid;
        int cc = c ^ (((c >> 5) & 1) << 1);      // byte-bit5 flip == chunk-bit1
        int s = cc >> 6;                          // subtile idx 0..15
        int ks = s >> 3, gg = s & 7;              // K-half, rowgroup
        int row  = gg * 16 + ((cc >> 2) & 15);
        int colE = ks * 32 + ((cc & 3) << 3);
        offA[i] = (long)(rowBase + row) * lda + colE;
        offB[i] = (long)(colBase + row) * ldb + colE;
    }

#define STA(buf, vv, i) ld_lds16(Aop + offA[i] + (long)(vv) * 64, &lds[buf][0][(i) * 2048 + wid * 512])
#define STB(buf, vv, i) ld_lds16(Bop + offB[i] + (long)(vv) * 64, &lds[buf][1][(i) * 2048 + wid * 512])

    // prologue: H0(0), H1(0), H0(1)  -> 12 outstanding loads per wave
    STA(0, 0, 0); STA(0, 0, 1); STB(0, 0, 0); STB(0, 0, 1);
    STA(0, 0, 2); STA(0, 0, 3); STB(0, 0, 2); STB(0, 0, 3);
    STA(1, 1, 0); STA(1, 1, 1); STB(1, 1, 0); STB(1, 1, 1);

    f32x4 acc[4][4] = {};

    for (int v = 0; v < NT; ++v) {
        const int b = v & 1;
        const char* lA = (const char*)&lds[b][0][0];
        const char* lB = (const char*)&lds[b][1][0];

        // ---- phase ks=0: needs H0(v); issue H1(v+1) (buf b^1 ks1-half,
        // whose last readers were ks1(v-1), complete before this barrier)
        if (v < NT - 1) asm volatile("s_waitcnt vmcnt(8)" ::: "memory");
        else            asm volatile("s_waitcnt vmcnt(4)" ::: "memory");
        __builtin_amdgcn_s_barrier();
        if (v + 1 < NT) {
            STA(b ^ 1, v + 1, 2); STA(b ^ 1, v + 1, 3);
            STB(b ^ 1, v + 1, 2); STB(b ^ 1, v + 1, 3);
        }
        {
            s16x8 af[4], bfm[4];
#pragma unroll
            for (int t = 0; t < 4; ++t)
                af[t] = *(const s16x8*)(lA + ((0 * 8 + wm * 4 + t) << 10) + ib);
#pragma unroll
            for (int t = 0; t < 4; ++t)
                bfm[t] = *(const s16x8*)(lB + ((0 * 8 + wn * 4 + t) << 10) + ib);
            __builtin_amdgcn_s_setprio(1);
#pragma unroll
            for (int i = 0; i < 4; i++)
#pragma unroll
                for (int j = 0; j < 4; j++)
                    acc[i][j] = __builtin_amdgcn_mfma_f32_16x16x32_bf16(
                        af[i], bfm[j], acc[i][j], 0, 0, 0);
            __builtin_amdgcn_s_setprio(0);
        }

        // ---- phase ks=1: needs H1(v); issue H0(v+2) (buf b ks0-half,
        // whose last readers were ks0(v), complete before this barrier)
        if (v < NT - 1) asm volatile("s_waitcnt vmcnt(8)" ::: "memory");
        else            asm volatile("s_waitcnt vmcnt(0)" ::: "memory");
        __builtin_amdgcn_s_barrier();
        if (v + 2 < NT) {
            STA(b, v + 2, 0); STA(b, v + 2, 1);
            STB(b, v + 2, 0); STB(b, v + 2, 1);
        }
        {
            s16x8 af[4], bfm[4];
#pragma unroll
            for (int t = 0; t < 4; ++t)
                af[t] = *(const s16x8*)(lA + ((1 * 8 + wm * 4 + t) << 10) + ib);
#pragma unroll
            for (int t = 0; t < 4; ++t)
                bfm[t] = *(const s16x8*)(lB + ((1 * 8 + wn * 4 + t) << 10) + ib);
            __builtin_amdgcn_s_setprio(1);
#pragma unroll
            for (int i = 0; i < 4; i++)
#pragma unroll
                for (int j = 0; j < 4; j++)
                    acc[i][j] = __builtin_amdgcn_mfma_f32_16x16x32_bf16(
                        af[i], bfm[j], acc[i][j], 0, 0, 0);
            __builtin_amdgcn_s_setprio(0);
        }
    }
#undef STA
#undef STB

    // Epilogue. D mapping: col = lane&15, row = quad*4+reg (guide §3).
    if (MODE == 0) {
        if (z < 2) {
            ushort* Cz = Cb + (long)z * sC;
#pragma unroll
            for (int i = 0; i < 4; i++) {
                int r0 = rowBase + wm * 64 + i * 16 + quad * 4;
#pragma unroll
                for (int j = 0; j < 4; j++) {
                    int c = colBase + wn * 64 + j * 16 + lr;
#pragma unroll
                    for (int reg = 0; reg < 4; reg++)
                        Cz[(long)(r0 + reg) * ldc + c] = f2bf(acc[i][j][reg]);
                }
            }
        } else {
            // v-projection: store transposed vT[b][col][row]
#pragma unroll
            for (int i = 0; i < 4; i++) {
                int r0 = rowBase + wm * 64 + i * 16 + quad * 4;
                int bidx = r0 >> 11;
                int jj = r0 & 2047;
                ushort* Cz = Cb2 + (long)bidx * DIM * LSP;
#pragma unroll
                for (int j = 0; j < 4; j++) {
                    int c = colBase + wn * 64 + j * 16 + lr;
                    ushort4 o;
                    o.x = f2bf(acc[i][j][0]); o.y = f2bf(acc[i][j][1]);
                    o.z = f2bf(acc[i][j][2]); o.w = f2bf(acc[i][j][3]);
                    *(ushort4*)(Cz + (long)c * LSP + jj) = o;
                }
            }
        }
    } else if (MODE == 2) {
        ushort* Cz = Cb + (long)z * sC;
        float* lz = lsum + (long)z * M;
#pragma unroll
        for (int i = 0; i < 4; i++) {
            int r0 = rowBase + wm * 64 + i * 16 + quad * 4;
#pragma unroll
            for (int reg = 0; reg < 4; reg++) {
                float s = 0.f;
#pragma unroll
                for (int j = 0; j < 4; j++) {
                    int c = colBase + wn * 64 + j * 16 + lr;
                    float e = __expf(acc[i][j][reg] * scale);  // |logit|<=sqrt(768): no max needed
                    s += e;
                    Cz[(long)(r0 + reg) * ldc + c] = f2bf(e);
                }
                for (int m = 1; m < 16; m <<= 1) s += __shfl_xor(s, m, 64);
                if (lr == 0) atomicAdd(&lz[r0 + reg], s);
            }
        }
    } else { // MODE 3 split-K
        float* Cz = (hz ? Cf2 : Cf) + (long)bz * sC;
#pragma unroll
        for (int i = 0; i < 4; i++) {
            int r0 = rowBase + wm * 64 + i * 16 + quad * 4;
#pragma unroll
            for (int j = 0; j < 4; j++) {
                int c = colBase + wn * 64 + j * 16 + lr;
#pragma unroll
                for (int reg = 0; reg < 4; reg++)
                    Cz[(long)(r0 + reg) * ldc + c] = acc[i][j][reg];
            }
        }
    }
}

// ---------------------------------------------------------------------------
// In-place LayerNorm over DIM=768 bf16 values. One wave per row (12 elem/lane).
// ---------------------------------------------------------------------------
__global__ __launch_bounds__(256) void ln_inplace(
    ushort* __restrict__ X, const float* __restrict__ gamma,
    const float* __restrict__ beta)
{
    int wid = threadIdx.x >> 6, lane = threadIdx.x & 63;
    int row = blockIdx.x * 4 + wid;
    ushort* xp = X + (long)row * DIM;
    float v[12];
    float s = 0.f;
#pragma unroll
    for (int c = 0; c < 12; c++) { v[c] = bf2f(xp[c * 64 + lane]); s += v[c]; }
    for (int m = 1; m < 64; m <<= 1) s += __shfl_xor(s, m, 64);
    float mean = s * (1.0f / 768.0f);
    float q = 0.f;
#pragma unroll
    for (int c = 0; c < 12; c++) { float d = v[c] - mean; q += d * d; }
    for (int m = 1; m < 64; m <<= 1) q += __shfl_xor(q, m, 64);
    float rstd = rsqrtf(q * (1.0f / 768.0f) + LN_EPS);
#pragma unroll
    for (int c = 0; c < 12; c++) {
        int idx = c * 64 + lane;
        float y = (v[c] - mean) * rstd * gamma[idx] + beta[idx];
        xp[idx] = f2bf(y);
    }
}

// ---------------------------------------------------------------------------
// out[row] = softmax_over_d( (O0[row]+O1[row]) / l[row] ). One wave per row.
// ---------------------------------------------------------------------------
__global__ __launch_bounds__(256) void final_softmax(
    const float* __restrict__ O0, const float* __restrict__ O1,
    const float* __restrict__ l, float* __restrict__ out)
{
    int wid = threadIdx.x >> 6, lane = threadIdx.x & 63;
    int row = blockIdx.x * 4 + wid;
    long base = (long)row * DIM;
    float inv = 1.0f / l[row];
    float v[12]; float mx = -1e30f;
#pragma unroll
    for (int c = 0; c < 12; c++) {
        v[c] = (O0[base + c * 64 + lane] + O1[base + c * 64 + lane]) * inv;
        mx = fmaxf(mx, v[c]);
    }
    for (int m = 1; m < 64; m <<= 1) mx = fmaxf(mx, __shfl_xor(mx, m, 64));
    float s = 0.f;
#pragma unroll
    for (int c = 0; c < 12; c++) { v[c] = __expf(v[c] - mx); s += v[c]; }
    for (int m = 1; m < 64; m <<= 1) s += __shfl_xor(s, m, 64);
    float invs = 1.0f / s;
#pragma unroll
    for (int c = 0; c < 12; c++) out[base + c * 64 + lane] = v[c] * invs;
}

// ---------------------------------------------------------------------------
extern "C" void kernel_launch(void* const* d_in, const int* in_sizes, int n_in,
                              void* d_out, int out_size, void* d_ws, size_t ws_size,
                              hipStream_t stream)
{
    const float* Q  = (const float*)d_in[0];
    const float* K_ = (const float*)d_in[1];
    const float* V  = (const float*)d_in[2];
    const float* Wq = (const float*)d_in[3];
    const float* Wk = (const float*)d_in[4];
    const float* Wv = (const float*)d_in[5];
    const float* g  = (const float*)d_in[6];
    const float* b  = (const float*)d_in[7];
    float* out = (float*)d_out;

    char* ws = (char*)d_ws;
    // Workspace layout (bytes). Total ~104.3 MB.
    // P aliases X (lifetime-disjoint); O1 aliases qb+kb (dead after QK).
    ushort* Xq  = (ushort*)(ws + 0);            // 12,582,912 each (Xq,Xk,Xv contig)
    ushort* Wqb = (ushort*)(ws + 37748736);     // 1,179,648 each (contig)
    ushort* qb  = (ushort*)(ws + 41287680);     // 12,582,912 each (qb,kb contig)
    ushort* kb  = (ushort*)(ws + 53870592);
    ushort* vT  = (ushort*)(ws + 66453504);     // 12,582,912
    float*  O0  = (float*)(ws + 79036416);      // 25,165,824
    float*  l   = (float*)(ws + 104202240);     // 32,768
    ushort* P   = (ushort*)(ws + 0);            // 33,554,432 (alias X)
    float*  O1  = (float*)(ws + 41287680);      // 25,165,824 (alias qb+kb)

    (void)in_sizes; (void)n_in; (void)out_size; (void)ws_size;

    hipMemsetAsync(l, 0, NROWS * sizeof(float), stream);

    // 1) gather sparsified rows -> bf16 (z = Q/K/V)
    pack3<<<dim3(6144, 1, 3), 256, 0, stream>>>(Q, K_, V, Xq);
    // 2) weights -> bf16 (z = Wq/Wk/Wv)
    conv3<<<dim3(576, 1, 3), 256, 0, stream>>>(Wq, Wk, Wv, Wqb);

    // 3) projections: z in {q,k,v}; v stores transposed (vT). 1152 blocks.
    gemm_bt<0, 12><<<dim3(DIM / 128, NROWS / 128, 3), 256, 0, stream>>>(
        Xq, Wqb, qb, vT, nullptr, nullptr, nullptr,
        NROWS, DIM, DIM, DIM,
        (long)NROWS * DIM, (long)DIM * DIM, (long)NROWS * DIM, DIM, 0.f);

    // 4) LayerNorm q and k in place (qb,kb contiguous: 16384 rows)
    ln_inplace<<<4096, 256, 0, stream>>>(qb, g, b);

    // 5) P = exp(scale * q k^T), row-sums into l  (1024 blocks = 4/CU)
    gemm_bt<2, 12><<<dim3(LSP / 128, LSP / 128, BATCH), 256, 0, stream>>>(
        qb, kb, P, nullptr, nullptr, nullptr, l,
        LSP, LSP, DIM, DIM,
        (long)LSP * DIM, (long)LSP * DIM, (long)LSP * LSP, LSP, ATT_SCALE);

    // 6) O = P @ v, split-K x2 (z = batch*2 + half), B operand = vT (768 blocks)
    gemm_bt<3, 16><<<dim3(DIM / 128, LSP / 128, BATCH * 2), 256, 0, stream>>>(
        P, vT, nullptr, nullptr, O0, O1, nullptr,
        LSP, DIM, LSP, LSP,
        (long)LSP * LSP, (long)DIM * LSP, (long)LSP * DIM, DIM, 0.f);

    // 7) out = softmax_d((O0+O1) / l)
    final_softmax<<<2048, 256, 0, stream>>>(O0, O1, l, out);
}